// Round 3
// baseline (1170.547 us; speedup 1.0000x reference)
//
#include <hip/hip_runtime.h>
#include <hip/hip_bf16.h>

// Problem constants
#define NTOK 294                    // AGENT*WIN*WIN = 6*49
#define NB   256                    // X*Y = 16*16
#define NN   (NTOK*NTOK)            // 86436
#define QKVSZ (NB*8*NTOK*32)        // floats per q/k/v buffer
#define ROWS_M (NB*NTOK)            // 75264
// Workspace (floats): [q | k | v | biasT] ~234 MB. attn overwrites q in-place.

typedef __bf16 bf16x8 __attribute__((ext_vector_type(8)));
typedef float  f32x4  __attribute__((ext_vector_type(4)));

union Bf8 { bf16x8 v; unsigned short u[8]; };

__device__ inline unsigned short f2bf(float f) {      // RNE fp32 -> bf16
    unsigned int u = __float_as_uint(f);
    return (unsigned short)((u + 0x7FFFu + ((u >> 16) & 1u)) >> 16);
}

// ---------------- Kernel A: bias table expand, transposed to [h][j][i] ----
__global__ void bias_expand(const float* __restrict__ table,
                            const int* __restrict__ rel,
                            float* __restrict__ biasT) {
    int t = blockIdx.x * 256 + threadIdx.x;   // t = j*294 + i
    if (t >= NN) return;
    int j = t / NTOK;
    int i = t - j * NTOK;
    int idx = rel[i * NTOK + j];
    const float* src = table + idx * 8;
#pragma unroll
    for (int h = 0; h < 8; ++h)
        biasT[h * NN + t] = src[h];           // coalesced writes
}

// ---------------- Kernel B: fused permute + QKV projection (bf16 MFMA) ---
// M=75264, Ncols=768, K=256. 128x128 tile, BK=64, 4 waves x (64x64).
// A and B^T both staged [128][64] bf16 in LDS, XOR-swizzled (T2):
//   ushort idx ^= (row&7)<<3  -> fragment ds_read_b128 is conflict-free-ish.
// Fragment maps (measured, m89/m91): A row=l&15,k=(l>>4)*8+e; B col=l&15,
// same k; D col=l&15,row=(l>>4)*4+reg.
__global__ __launch_bounds__(256) void qkv_gemm_mfma(const float* __restrict__ x,
                                                     const float* __restrict__ wqkv,
                                                     float* __restrict__ qb,
                                                     float* __restrict__ kb,
                                                     float* __restrict__ vb) {
    __shared__ unsigned short As[128 * 64];
    __shared__ unsigned short Bs[128 * 64];
    const int t    = threadIdx.x;
    const int lane = t & 63;
    const int w    = t >> 6;
    const int wm   = w >> 1, wn = w & 1;

    // A staging: thread t loads row r, 32 consecutive k (one 128B segment)
    const int r  = t >> 1;
    const int h2 = t & 1;
    int m  = blockIdx.x * 128 + r;
    int Bi = m / NTOK, n = m - Bi * NTOK;
    int l  = n / 49,   ww = n - l * 49;
    int xx = Bi >> 4,  yy = Bi & 15;
    const float* arow = x + (size_t)((((l * 16 + xx) * 16 + yy) * 49 + ww) << 8) + h2 * 32;

    // B staging: thread t loads rows kl0..kl0+7 (k), cols n4..n4+3 -> transpose-pack
    const int n4  = (t & 31) * 4;
    const int kl0 = (t >> 5) * 8;
    const int cb  = blockIdx.y * 128;
    const float* bsrc = wqkv + (size_t)kl0 * 768 + cb + n4;

    f32x4 acc[4][4];
#pragma unroll
    for (int i = 0; i < 4; ++i)
#pragma unroll
        for (int j = 0; j < 4; ++j) acc[i][j] = (f32x4){0.f, 0.f, 0.f, 0.f};

    for (int kk = 0; kk < 256; kk += 64) {
        // -- global loads + convert (no LDS touch yet)
        Bf8 apk[4];
#pragma unroll
        for (int c = 0; c < 4; ++c) {
            float4 f0 = *(const float4*)(arow + kk + c * 8);
            float4 f1 = *(const float4*)(arow + kk + c * 8 + 4);
            apk[c].u[0] = f2bf(f0.x); apk[c].u[1] = f2bf(f0.y);
            apk[c].u[2] = f2bf(f0.z); apk[c].u[3] = f2bf(f0.w);
            apk[c].u[4] = f2bf(f1.x); apk[c].u[5] = f2bf(f1.y);
            apk[c].u[6] = f2bf(f1.z); apk[c].u[7] = f2bf(f1.w);
        }
        float bv[8][4];
#pragma unroll
        for (int e = 0; e < 8; ++e) {
            float4 f = *(const float4*)(bsrc + (size_t)(kk + e) * 768);
            bv[e][0] = f.x; bv[e][1] = f.y; bv[e][2] = f.z; bv[e][3] = f.w;
        }
        __syncthreads();                       // prev iteration's LDS reads done
        // -- LDS writes (swizzled)
#pragma unroll
        for (int c = 0; c < 4; ++c) {
            int idx = (r * 64 + h2 * 32 + c * 8) ^ ((r & 7) << 3);
            *(bf16x8*)&As[idx] = apk[c].v;
        }
#pragma unroll
        for (int j = 0; j < 4; ++j) {
            Bf8 pk;
#pragma unroll
            for (int e = 0; e < 8; ++e) pk.u[e] = f2bf(bv[e][j]);
            int nn  = n4 + j;
            int idx = (nn * 64 + kl0) ^ ((nn & 7) << 3);
            *(bf16x8*)&Bs[idx] = pk.v;
        }
        __syncthreads();
        // -- MFMA: 2 k-slices of 32
        const int lrow = lane & 15;
        const int kofs = (lane >> 4) * 8;
#pragma unroll
        for (int ks = 0; ks < 2; ++ks) {
            bf16x8 af[4], bf[4];
#pragma unroll
            for (int fi = 0; fi < 4; ++fi) {
                int rr  = wm * 64 + fi * 16 + lrow;
                int idx = (rr * 64 + ks * 32 + kofs) ^ ((rr & 7) << 3);
                af[fi] = *(const bf16x8*)&As[idx];
            }
#pragma unroll
            for (int fj = 0; fj < 4; ++fj) {
                int rr  = wn * 64 + fj * 16 + lrow;
                int idx = (rr * 64 + ks * 32 + kofs) ^ ((rr & 7) << 3);
                bf[fj] = *(const bf16x8*)&Bs[idx];
            }
#pragma unroll
            for (int fi = 0; fi < 4; ++fi)
#pragma unroll
                for (int fj = 0; fj < 4; ++fj)
                    acc[fi][fj] = __builtin_amdgcn_mfma_f32_16x16x32_bf16(
                        af[fi], bf[fj], acc[fi][fj], 0, 0, 0);
        }
    }

    // -- epilogue: scatter to q/k/v in (B,h,N,32) fp32, scale on q
    const float scale = 0.17677669529663687f;  // dh^-0.5
    const int rq   = lane >> 4;
    const int cidx = lane & 15;
#pragma unroll
    for (int fi = 0; fi < 4; ++fi) {
#pragma unroll
        for (int reg = 0; reg < 4; ++reg) {
            int mm  = blockIdx.x * 128 + wm * 64 + fi * 16 + rq * 4 + reg;
            int Bi2 = mm / NTOK, n2 = mm - Bi2 * NTOK;
#pragma unroll
            for (int fj = 0; fj < 4; ++fj) {
                int c     = cb + wn * 64 + fj * 16 + cidx;
                int which = c >> 8;
                int rr    = c & 255;
                int hh    = rr >> 5, di = rr & 31;
                float* dst = which == 0 ? qb : (which == 1 ? kb : vb);
                float vvv  = acc[fi][fj][reg] * (which == 0 ? scale : 1.0f);
                dst[(size_t)((Bi2 * 8 + hh) * NTOK + n2) * 32 + di] = vvv;
            }
        }
    }
}

// ---------------- Kernel C: attention per (B,h), flash-style (fp32) ------
// One block = one (B,h). 320 threads: thread i owns query row i (294 active).
// K,V staged in LDS (75 KB). Max-free softmax (|sim| small analytically).
__global__ __launch_bounds__(320) void attn_fused(float* __restrict__ qbuf,
                                                  const float* __restrict__ kbuf,
                                                  const float* __restrict__ vbuf,
                                                  const float* __restrict__ biasT) {
    __shared__ float ks[NTOK * 32];
    __shared__ float vs[NTOK * 32];
    const int bh = blockIdx.x;
    const int h  = bh & 7;
    const float* kg = kbuf + (size_t)bh * (NTOK * 32);
    const float* vg = vbuf + (size_t)bh * (NTOK * 32);
    for (int i4 = threadIdx.x; i4 < NTOK * 8; i4 += 320) {
        ((float4*)ks)[i4] = ((const float4*)kg)[i4];
        ((float4*)vs)[i4] = ((const float4*)vg)[i4];
    }
    __syncthreads();

    const int row = threadIdx.x;
    if (row >= NTOK) return;
    float* qrow = qbuf + (size_t)bh * (NTOK * 32) + row * 32;
    float q[32];
#pragma unroll
    for (int d = 0; d < 32; d += 4) {
        float4 tq = *(const float4*)(qrow + d);
        q[d] = tq.x; q[d + 1] = tq.y; q[d + 2] = tq.z; q[d + 3] = tq.w;
    }
    float accv[32];
#pragma unroll
    for (int d = 0; d < 32; ++d) accv[d] = 0.f;
    float lsum = 0.f;
    const float* bT = biasT + (size_t)h * NN + row;   // + j*294, lane-coalesced

    float bcur = bT[0];
    for (int j = 0; j < NTOK; ++j) {
        float bnext = (j < NTOK - 1) ? bT[(size_t)(j + 1) * NTOK] : 0.f;  // prefetch
        const float* kr = ks + j * 32;
        float s0 = 0.f, s1 = 0.f, s2 = 0.f, s3 = 0.f;
#pragma unroll
        for (int d = 0; d < 32; d += 4) {
            float4 kv = *(const float4*)(kr + d);     // uniform addr -> broadcast
            s0 += q[d] * kv.x;  s1 += q[d + 1] * kv.y;
            s2 += q[d + 2] * kv.z; s3 += q[d + 3] * kv.w;
        }
        float s = (s0 + s1) + (s2 + s3) + bcur;
        float p = __expf(s);
        lsum += p;
        const float* vr = vs + j * 32;
#pragma unroll
        for (int d = 0; d < 32; d += 4) {
            float4 vv = *(const float4*)(vr + d);
            accv[d] += p * vv.x;  accv[d + 1] += p * vv.y;
            accv[d + 2] += p * vv.z; accv[d + 3] += p * vv.w;
        }
        bcur = bnext;
    }
    float inv = 1.0f / lsum;
#pragma unroll
    for (int d = 0; d < 32; d += 4) {
        float4 o;
        o.x = accv[d] * inv; o.y = accv[d + 1] * inv;
        o.z = accv[d + 2] * inv; o.w = accv[d + 3] * inv;
        *(float4*)(qrow + d) = o;
    }
}

// ---------------- Kernel D: out projection + inverse permute (bf16 MFMA) -
// M=75264, Ncols=256, K=256. Same micro-kernel as Kernel B.
__global__ __launch_bounds__(256) void out_gemm_mfma(const float* __restrict__ attn,
                                                     const float* __restrict__ wout,
                                                     float* __restrict__ out) {
    __shared__ unsigned short As[128 * 64];
    __shared__ unsigned short Bs[128 * 64];
    const int t    = threadIdx.x;
    const int lane = t & 63;
    const int w    = t >> 6;
    const int wm   = w >> 1, wn = w & 1;

    // A staging: attn is (B,h,N,32); k = hh*32+di so each 32-float k-segment
    // is contiguous at abase + hh*(NTOK*32).
    const int r  = t >> 1;
    const int h2 = t & 1;
    int m  = blockIdx.x * 128 + r;
    int Bi = m / NTOK, n = m - Bi * NTOK;
    const float* abase = attn + (size_t)Bi * (8 * NTOK * 32) + n * 32;

    const int n4  = (t & 31) * 4;
    const int kl0 = (t >> 5) * 8;
    const int cb  = blockIdx.y * 128;
    const float* bsrc = wout + (size_t)kl0 * 256 + cb + n4;

    f32x4 acc[4][4];
#pragma unroll
    for (int i = 0; i < 4; ++i)
#pragma unroll
        for (int j = 0; j < 4; ++j) acc[i][j] = (f32x4){0.f, 0.f, 0.f, 0.f};

    for (int kk = 0; kk < 256; kk += 64) {
        const float* asrc = abase + (size_t)((kk >> 5) + h2) * (NTOK * 32);
        Bf8 apk[4];
#pragma unroll
        for (int c = 0; c < 4; ++c) {
            float4 f0 = *(const float4*)(asrc + c * 8);
            float4 f1 = *(const float4*)(asrc + c * 8 + 4);
            apk[c].u[0] = f2bf(f0.x); apk[c].u[1] = f2bf(f0.y);
            apk[c].u[2] = f2bf(f0.z); apk[c].u[3] = f2bf(f0.w);
            apk[c].u[4] = f2bf(f1.x); apk[c].u[5] = f2bf(f1.y);
            apk[c].u[6] = f2bf(f1.z); apk[c].u[7] = f2bf(f1.w);
        }
        float bv[8][4];
#pragma unroll
        for (int e = 0; e < 8; ++e) {
            float4 f = *(const float4*)(bsrc + (size_t)(kk + e) * 256);
            bv[e][0] = f.x; bv[e][1] = f.y; bv[e][2] = f.z; bv[e][3] = f.w;
        }
        __syncthreads();
#pragma unroll
        for (int c = 0; c < 4; ++c) {
            int idx = (r * 64 + h2 * 32 + c * 8) ^ ((r & 7) << 3);
            *(bf16x8*)&As[idx] = apk[c].v;
        }
#pragma unroll
        for (int j = 0; j < 4; ++j) {
            Bf8 pk;
#pragma unroll
            for (int e = 0; e < 8; ++e) pk.u[e] = f2bf(bv[e][j]);
            int nn  = n4 + j;
            int idx = (nn * 64 + kl0) ^ ((nn & 7) << 3);
            *(bf16x8*)&Bs[idx] = pk.v;
        }
        __syncthreads();
        const int lrow = lane & 15;
        const int kofs = (lane >> 4) * 8;
#pragma unroll
        for (int ks = 0; ks < 2; ++ks) {
            bf16x8 af[4], bf[4];
#pragma unroll
            for (int fi = 0; fi < 4; ++fi) {
                int rr  = wm * 64 + fi * 16 + lrow;
                int idx = (rr * 64 + ks * 32 + kofs) ^ ((rr & 7) << 3);
                af[fi] = *(const bf16x8*)&As[idx];
            }
#pragma unroll
            for (int fj = 0; fj < 4; ++fj) {
                int rr  = wn * 64 + fj * 16 + lrow;
                int idx = (rr * 64 + ks * 32 + kofs) ^ ((rr & 7) << 3);
                bf[fj] = *(const bf16x8*)&Bs[idx];
            }
#pragma unroll
            for (int fi = 0; fi < 4; ++fi)
#pragma unroll
                for (int fj = 0; fj < 4; ++fj)
                    acc[fi][fj] = __builtin_amdgcn_mfma_f32_16x16x32_bf16(
                        af[fi], bf[fj], acc[fi][fj], 0, 0, 0);
        }
    }

    // -- epilogue: inverse window permute straight into d_out
    const int rq   = lane >> 4;
    const int cidx = lane & 15;
#pragma unroll
    for (int fi = 0; fi < 4; ++fi) {
#pragma unroll
        for (int reg = 0; reg < 4; ++reg) {
            int mm  = blockIdx.x * 128 + wm * 64 + fi * 16 + rq * 4 + reg;
            int Bi2 = mm / NTOK, n2 = mm - Bi2 * NTOK;
            int l2  = n2 / 49,   w2 = n2 - l2 * 49;
            int xx2 = Bi2 >> 4,  yy2 = Bi2 & 15;
            float* orow = out + (size_t)((((l2 * 16 + xx2) * 16 + yy2) * 49 + w2) << 8);
#pragma unroll
            for (int fj = 0; fj < 4; ++fj) {
                int c = cb + wn * 64 + fj * 16 + cidx;
                orow[c] = acc[fi][fj][reg];
            }
        }
    }
}

extern "C" void kernel_launch(void* const* d_in, const int* in_sizes, int n_in,
                              void* d_out, int out_size, void* d_ws, size_t ws_size,
                              hipStream_t stream) {
    const float* x     = (const float*)d_in[0];
    const float* wqkv  = (const float*)d_in[1];
    const float* wout  = (const float*)d_in[2];
    const float* table = (const float*)d_in[3];
    const int*   rel   = (const int*)d_in[4];
    float* out = (float*)d_out;

    float* ws    = (float*)d_ws;
    float* qb    = ws;                        // QKVSZ floats; attn out overwrites
    float* kb    = ws + (size_t)QKVSZ;
    float* vb    = ws + (size_t)2 * QKVSZ;
    float* biasT = ws + (size_t)3 * QKVSZ;    // 8*NN floats

    hipLaunchKernelGGL(bias_expand, dim3((NN + 255) / 256), dim3(256), 0, stream,
                       table, rel, biasT);
    hipLaunchKernelGGL(qkv_gemm_mfma, dim3(ROWS_M / 128, 6), dim3(256), 0, stream,
                       x, wqkv, qb, kb, vb);
    hipLaunchKernelGGL(attn_fused, dim3(NB * 8), dim3(320), 0, stream,
                       qb, kb, vb, biasT);
    hipLaunchKernelGGL(out_gemm_mfma, dim3(ROWS_M / 128, 2), dim3(256), 0, stream,
                       qb, wout, out);
}

// Round 6
// 430.409 us; speedup vs baseline: 2.7196x; 2.7196x over previous
//
#include <hip/hip_runtime.h>
#include <hip/hip_bf16.h>

// Problem constants
#define NTOK 294                    // AGENT*WIN*WIN = 6*49
#define NB   256                    // X*Y = 16*16
#define NN   (NTOK*NTOK)            // 86436
#define ROWS_M (NB*NTOK)            // 75264
#define USN  19267584ULL            // 2048*294*32 ushorts per q/k/vt buffer
// ws layout (bytes): qb_us | kb_us | vt_us | biasQ(f32)  ~118 MB total.
// attn writes O bf16 in-place over qb (each block owns its rows exclusively).

typedef __bf16 bf16x8 __attribute__((ext_vector_type(8)));
typedef float  f32x4  __attribute__((ext_vector_type(4)));
typedef unsigned short ushort_t;

union Bf8 { bf16x8 v; unsigned short u[8]; };

__device__ inline unsigned short f2bf(float f) {      // RNE fp32 -> bf16
    unsigned int u = __float_as_uint(f);
    return (unsigned short)((u + 0x7FFFu + ((u >> 16) & 1u)) >> 16);
}

// ---------------- Kernel A: bias expand to [h][q][k] fp32 ----------------
__global__ void bias_expand(const float* __restrict__ table,
                            const int* __restrict__ rel,
                            float* __restrict__ biasQ) {
    int t = blockIdx.x * 256 + threadIdx.x;   // t = i*294 + j (q-major)
    if (t >= NN) return;
    int idx = rel[t];
    const float* src = table + idx * 8;
#pragma unroll
    for (int h = 0; h < 8; ++h)
        biasQ[h * NN + t] = src[h];           // coalesced writes per h
}

// ---------------- Kernel B: fused permute + QKV projection (bf16 MFMA) ---
// Outputs bf16: q scaled [bh][n][32], k [bh][n][32], v TRANSPOSED [bh][32][n].
__global__ __launch_bounds__(256) void qkv_gemm_mfma(const float* __restrict__ x,
                                                     const float* __restrict__ wqkv,
                                                     ushort_t* __restrict__ qb,
                                                     ushort_t* __restrict__ kb,
                                                     ushort_t* __restrict__ vt) {
    __shared__ unsigned short As[128 * 64];
    __shared__ unsigned short Bs[128 * 64];
    const int t    = threadIdx.x;
    const int lane = t & 63;
    const int w    = t >> 6;
    const int wm   = w >> 1, wn = w & 1;

    const int r  = t >> 1;
    const int h2 = t & 1;
    int m  = blockIdx.x * 128 + r;
    int Bi = m / NTOK, n = m - Bi * NTOK;
    int l  = n / 49,   ww = n - l * 49;
    int xx = Bi >> 4,  yy = Bi & 15;
    const float* arow = x + (size_t)((((l * 16 + xx) * 16 + yy) * 49 + ww) << 8) + h2 * 32;

    const int n4  = (t & 31) * 4;
    const int kl0 = (t >> 5) * 8;
    const int cb  = blockIdx.y * 128;
    const float* bsrc = wqkv + (size_t)kl0 * 768 + cb + n4;

    f32x4 acc[4][4];
#pragma unroll
    for (int i = 0; i < 4; ++i)
#pragma unroll
        for (int j = 0; j < 4; ++j) acc[i][j] = (f32x4){0.f, 0.f, 0.f, 0.f};

    for (int kk = 0; kk < 256; kk += 64) {
        Bf8 apk[4];
#pragma unroll
        for (int c = 0; c < 4; ++c) {
            float4 f0 = *(const float4*)(arow + kk + c * 8);
            float4 f1 = *(const float4*)(arow + kk + c * 8 + 4);
            apk[c].u[0] = f2bf(f0.x); apk[c].u[1] = f2bf(f0.y);
            apk[c].u[2] = f2bf(f0.z); apk[c].u[3] = f2bf(f0.w);
            apk[c].u[4] = f2bf(f1.x); apk[c].u[5] = f2bf(f1.y);
            apk[c].u[6] = f2bf(f1.z); apk[c].u[7] = f2bf(f1.w);
        }
        float bv[8][4];
#pragma unroll
        for (int e = 0; e < 8; ++e) {
            float4 f = *(const float4*)(bsrc + (size_t)(kk + e) * 768);
            bv[e][0] = f.x; bv[e][1] = f.y; bv[e][2] = f.z; bv[e][3] = f.w;
        }
        __syncthreads();
#pragma unroll
        for (int c = 0; c < 4; ++c) {
            int idx = (r * 64 + h2 * 32 + c * 8) ^ ((r & 7) << 3);
            *(bf16x8*)&As[idx] = apk[c].v;
        }
#pragma unroll
        for (int j = 0; j < 4; ++j) {
            Bf8 pk;
#pragma unroll
            for (int e = 0; e < 8; ++e) pk.u[e] = f2bf(bv[e][j]);
            int nn  = n4 + j;
            int idx = (nn * 64 + kl0) ^ ((nn & 7) << 3);
            *(bf16x8*)&Bs[idx] = pk.v;
        }
        __syncthreads();
        const int lrow = lane & 15;
        const int kofs = (lane >> 4) * 8;
#pragma unroll
        for (int ks = 0; ks < 2; ++ks) {
            bf16x8 af[4], bfr[4];
#pragma unroll
            for (int fi = 0; fi < 4; ++fi) {
                int rr  = wm * 64 + fi * 16 + lrow;
                int idx = (rr * 64 + ks * 32 + kofs) ^ ((rr & 7) << 3);
                af[fi] = *(const bf16x8*)&As[idx];
            }
#pragma unroll
            for (int fj = 0; fj < 4; ++fj) {
                int rr  = wn * 64 + fj * 16 + lrow;
                int idx = (rr * 64 + ks * 32 + kofs) ^ ((rr & 7) << 3);
                bfr[fj] = *(const bf16x8*)&Bs[idx];
            }
#pragma unroll
            for (int fi = 0; fi < 4; ++fi)
#pragma unroll
                for (int fj = 0; fj < 4; ++fj)
                    acc[fi][fj] = __builtin_amdgcn_mfma_f32_16x16x32_bf16(
                        af[fi], bfr[fj], acc[fi][fj], 0, 0, 0);
        }
    }

    const float scale = 0.17677669529663687f;  // dh^-0.5
    const int rq   = lane >> 4;
    const int cidx = lane & 15;
#pragma unroll
    for (int fi = 0; fi < 4; ++fi) {
#pragma unroll
        for (int reg = 0; reg < 4; ++reg) {
            int mm  = blockIdx.x * 128 + wm * 64 + fi * 16 + rq * 4 + reg;
            int Bi2 = mm / NTOK, n2 = mm - Bi2 * NTOK;
#pragma unroll
            for (int fj = 0; fj < 4; ++fj) {
                int c     = cb + wn * 64 + fj * 16 + cidx;
                int which = c >> 8;
                int rr    = c & 255;
                int hh    = rr >> 5, di = rr & 31;
                int bhi   = Bi2 * 8 + hh;
                if (which == 0) {
                    qb[((size_t)bhi * NTOK + n2) * 32 + di] = f2bf(acc[fi][fj][reg] * scale);
                } else if (which == 1) {
                    kb[((size_t)bhi * NTOK + n2) * 32 + di] = f2bf(acc[fi][fj][reg]);
                } else {
                    vt[((size_t)bhi * 32 + di) * NTOK + n2] = f2bf(acc[fi][fj][reg]);
                }
            }
        }
    }
}

// ---------------- Kernel C: MFMA flash attention ------------------------
// Grid (3 qtiles, 2048 bh). 256 thr = 4 waves; wave owns 32 q-rows (2x16).
// K LDS [320][40] bf16 (pad stride: conflict-free, 16B-aligned frags);
// Vt LDS [32][328]; P per-wave [16][40]. Padded keys masked via bias=-1e4.
#define S_KS 40
#define S_VS 328
#define S_PS 40
__global__ __launch_bounds__(256) void attn_mfma(ushort_t* __restrict__ qb,
                                                 const ushort_t* __restrict__ kb,
                                                 const ushort_t* __restrict__ vt,
                                                 const float* __restrict__ biasQ) {
    __shared__ ushort_t ks[320 * S_KS];
    __shared__ ushort_t vs[32 * S_VS];
    __shared__ ushort_t ps[4 * 16 * S_PS];
    const int qt = blockIdx.x, bh = blockIdx.y, h = bh & 7;
    const int tid = threadIdx.x;

    // stage K rows 0..293 (16 dwords each), zero rows 294..319
    const unsigned int* ksrc = (const unsigned int*)(kb + (size_t)bh * NTOK * 32);
    for (int t = tid; t < 294 * 16; t += 256) {
        int r = t >> 4, i = t & 15;
        *(unsigned int*)&ks[r * S_KS + 2 * i] = ksrc[t];
    }
    for (int t = tid; t < 26 * 16; t += 256) {
        int r = 294 + (t >> 4), i = t & 15;
        *(unsigned int*)&ks[r * S_KS + 2 * i] = 0u;
    }
    // stage Vt rows d=0..31 (147 dwords each), zero cols 294..327
    const unsigned int* vsrc = (const unsigned int*)(vt + (size_t)bh * 32 * NTOK);
    for (int t = tid; t < 32 * 147; t += 256) {
        int d = t / 147, i = t - d * 147;
        *(unsigned int*)&vs[d * S_VS + 2 * i] = vsrc[t];
    }
    for (int t = tid; t < 32 * 17; t += 256) {
        int d = t / 17, i = 147 + (t - d * 17);
        *(unsigned int*)&vs[d * S_VS + 2 * i] = 0u;
    }
    __syncthreads();

    const int wave = tid >> 6, lane = tid & 63;
    const int c = lane & 15, g = lane >> 4;
    const int q0 = qt * 128 + wave * 32;

    bf16x8 qf[2];
#pragma unroll
    for (int qs = 0; qs < 2; ++qs) {
        int qa = q0 + qs * 16 + c; if (qa > 293) qa = 293;
        qf[qs] = *(const bf16x8*)&qb[((size_t)bh * NTOK + qa) * 32 + 8 * g];
    }
    f32x4 acc_o[2][2];
    float psum[2][4];
#pragma unroll
    for (int qs = 0; qs < 2; ++qs) {
#pragma unroll
        for (int hf = 0; hf < 2; ++hf) acc_o[qs][hf] = (f32x4){0.f, 0.f, 0.f, 0.f};
#pragma unroll
        for (int rg = 0; rg < 4; ++rg) psum[qs][rg] = 0.f;
    }
    ushort_t* pw = ps + wave * 16 * S_PS;
    const float* bbase = biasQ + (size_t)h * NN;

    for (int kt = 0; kt < 10; ++kt) {
        const int kbase = kt * 32;
        bf16x8 kf[2], vf[2];
#pragma unroll
        for (int ksub = 0; ksub < 2; ++ksub)
            kf[ksub] = *(const bf16x8*)&ks[(kbase + ksub * 16 + c) * S_KS + 8 * g];
#pragma unroll
        for (int hf = 0; hf < 2; ++hf)
            vf[hf] = *(const bf16x8*)&vs[(hf * 16 + c) * S_VS + kbase + 8 * g];

#pragma unroll
        for (int qs = 0; qs < 2; ++qs) {
            f32x4 s0 = __builtin_amdgcn_mfma_f32_16x16x32_bf16(
                qf[qs], kf[0], (f32x4){0.f, 0.f, 0.f, 0.f}, 0, 0, 0);
            f32x4 s1 = __builtin_amdgcn_mfma_f32_16x16x32_bf16(
                qf[qs], kf[1], (f32x4){0.f, 0.f, 0.f, 0.f}, 0, 0, 0);
            const int qrb = q0 + qs * 16 + g * 4;
#pragma unroll
            for (int rg = 0; rg < 4; ++rg) {
                int qa = qrb + rg; if (qa > 293) qa = 293;
                const float* bp = bbase + (size_t)qa * NTOK;
#pragma unroll
                for (int ksub = 0; ksub < 2; ++ksub) {
                    int ka = kbase + ksub * 16 + c;
                    int kc = ka > 293 ? 293 : ka;
                    float bias = (ka < NTOK) ? bp[kc] : -1e4f;
                    float s = (ksub ? s1[rg] : s0[rg]) + bias;
                    float p = __expf(s);
                    psum[qs][rg] += p;
                    pw[(g * 4 + rg) * S_PS + ksub * 16 + c] = f2bf(p);
                }
            }
            // wave-synchronous LDS round-trip (no barrier needed)
            bf16x8 pa = *(const bf16x8*)&pw[c * S_PS + 8 * g];
#pragma unroll
            for (int hf = 0; hf < 2; ++hf)
                acc_o[qs][hf] = __builtin_amdgcn_mfma_f32_16x16x32_bf16(
                    pa, vf[hf], acc_o[qs][hf], 0, 0, 0);
        }
    }

    // 16-lane row-sum reduction (q row g*4+rg lives in 16-lane group g)
#pragma unroll
    for (int qs = 0; qs < 2; ++qs)
#pragma unroll
        for (int rg = 0; rg < 4; ++rg) {
            float v = psum[qs][rg];
            v += __shfl_xor(v, 1); v += __shfl_xor(v, 2);
            v += __shfl_xor(v, 4); v += __shfl_xor(v, 8);
            psum[qs][rg] = 1.0f / v;
        }

#pragma unroll
    for (int qs = 0; qs < 2; ++qs) {
        const int qrb = q0 + qs * 16 + g * 4;
#pragma unroll
        for (int rg = 0; rg < 4; ++rg) {
            int qa = qrb + rg;
            if (qa < NTOK) {
#pragma unroll
                for (int hf = 0; hf < 2; ++hf) {
                    float val = acc_o[qs][hf][rg] * psum[qs][rg];
                    qb[((size_t)bh * NTOK + qa) * 32 + hf * 16 + c] = f2bf(val);
                }
            }
        }
    }
}

// ---------------- Kernel D: out projection + inverse permute (bf16 MFMA) -
// A = attn output bf16 [bh][n][32] (in qb), gathered as (B*N, 256).
__global__ __launch_bounds__(256) void out_gemm_mfma(const ushort_t* __restrict__ ob,
                                                     const float* __restrict__ wout,
                                                     float* __restrict__ out) {
    __shared__ unsigned short As[128 * 64];
    __shared__ unsigned short Bs[128 * 64];
    const int t    = threadIdx.x;
    const int lane = t & 63;
    const int w    = t >> 6;
    const int wm   = w >> 1, wn = w & 1;

    const int r  = t >> 1;
    const int h2 = t & 1;
    int m  = blockIdx.x * 128 + r;
    int Bi = m / NTOK, n = m - Bi * NTOK;

    const int n4  = (t & 31) * 4;
    const int kl0 = (t >> 5) * 8;
    const int cb  = blockIdx.y * 128;
    const float* bsrc = wout + (size_t)kl0 * 256 + cb + n4;

    f32x4 acc[4][4];
#pragma unroll
    for (int i = 0; i < 4; ++i)
#pragma unroll
        for (int j = 0; j < 4; ++j) acc[i][j] = (f32x4){0.f, 0.f, 0.f, 0.f};

    for (int kk = 0; kk < 256; kk += 64) {
        const int h_idx = (kk >> 5) + h2;
        const ushort_t* asrc = ob + ((size_t)(Bi * 8 + h_idx) * NTOK + n) * 32;
        bf16x8 apk[4];
#pragma unroll
        for (int c = 0; c < 4; ++c) apk[c] = *(const bf16x8*)&asrc[c * 8];
        float bv[8][4];
#pragma unroll
        for (int e = 0; e < 8; ++e) {
            float4 f = *(const float4*)(bsrc + (size_t)(kk + e) * 256);
            bv[e][0] = f.x; bv[e][1] = f.y; bv[e][2] = f.z; bv[e][3] = f.w;
        }
        __syncthreads();
#pragma unroll
        for (int c = 0; c < 4; ++c) {
            int idx = (r * 64 + h2 * 32 + c * 8) ^ ((r & 7) << 3);
            *(bf16x8*)&As[idx] = apk[c];
        }
#pragma unroll
        for (int j = 0; j < 4; ++j) {
            Bf8 pk;
#pragma unroll
            for (int e = 0; e < 8; ++e) pk.u[e] = f2bf(bv[e][j]);
            int nn  = n4 + j;
            int idx = (nn * 64 + kl0) ^ ((nn & 7) << 3);
            *(bf16x8*)&Bs[idx] = pk.v;
        }
        __syncthreads();
        const int lrow = lane & 15;
        const int kofs = (lane >> 4) * 8;
#pragma unroll
        for (int ks = 0; ks < 2; ++ks) {
            bf16x8 af[4], bfr[4];
#pragma unroll
            for (int fi = 0; fi < 4; ++fi) {
                int rr  = wm * 64 + fi * 16 + lrow;
                int idx = (rr * 64 + ks * 32 + kofs) ^ ((rr & 7) << 3);
                af[fi] = *(const bf16x8*)&As[idx];
            }
#pragma unroll
            for (int fj = 0; fj < 4; ++fj) {
                int rr  = wn * 64 + fj * 16 + lrow;
                int idx = (rr * 64 + ks * 32 + kofs) ^ ((rr & 7) << 3);
                bfr[fj] = *(const bf16x8*)&Bs[idx];
            }
#pragma unroll
            for (int fi = 0; fi < 4; ++fi)
#pragma unroll
                for (int fj = 0; fj < 4; ++fj)
                    acc[fi][fj] = __builtin_amdgcn_mfma_f32_16x16x32_bf16(
                        af[fi], bfr[fj], acc[fi][fj], 0, 0, 0);
        }
    }

    const int rq   = lane >> 4;
    const int cidx = lane & 15;
#pragma unroll
    for (int fi = 0; fi < 4; ++fi) {
#pragma unroll
        for (int reg = 0; reg < 4; ++reg) {
            int mm  = blockIdx.x * 128 + wm * 64 + fi * 16 + rq * 4 + reg;
            int Bi2 = mm / NTOK, n2 = mm - Bi2 * NTOK;
            int l2  = n2 / 49,   w2 = n2 - l2 * 49;
            int xx2 = Bi2 >> 4,  yy2 = Bi2 & 15;
            float* orow = out + (size_t)((((l2 * 16 + xx2) * 16 + yy2) * 49 + w2) << 8);
#pragma unroll
            for (int fj = 0; fj < 4; ++fj) {
                int c = cb + wn * 64 + fj * 16 + cidx;
                orow[c] = acc[fi][fj][reg];
            }
        }
    }
}

extern "C" void kernel_launch(void* const* d_in, const int* in_sizes, int n_in,
                              void* d_out, int out_size, void* d_ws, size_t ws_size,
                              hipStream_t stream) {
    const float* x     = (const float*)d_in[0];
    const float* wqkv  = (const float*)d_in[1];
    const float* wout  = (const float*)d_in[2];
    const float* table = (const float*)d_in[3];
    const int*   rel   = (const int*)d_in[4];
    float* out = (float*)d_out;

    ushort_t* qb    = (ushort_t*)d_ws;
    ushort_t* kb    = qb + USN;
    ushort_t* vt    = kb + USN;
    float*    biasQ = (float*)(vt + USN);     // 8*NN floats

    hipLaunchKernelGGL(bias_expand, dim3((NN + 255) / 256), dim3(256), 0, stream,
                       table, rel, biasQ);
    hipLaunchKernelGGL(qkv_gemm_mfma, dim3(ROWS_M / 128, 6), dim3(256), 0, stream,
                       x, wqkv, qb, kb, vt);
    hipLaunchKernelGGL(attn_mfma, dim3(3, 2048), dim3(256), 0, stream,
                       qb, kb, vt, biasQ);
    hipLaunchKernelGGL(out_gemm_mfma, dim3(ROWS_M / 128, 2), dim3(256), 0, stream,
                       qb, wout, out);
}